// Round 2
// baseline (111.157 us; speedup 1.0000x reference)
//
#include <hip/hip_runtime.h>
#include <math.h>

#define EPS 1e-6f
constexpr int B    = 64;
constexpr int F    = 2;
constexpr int NC   = 10;
constexpr int ND   = 4;
constexpr int CHW  = 64 * 16 * 16;   // 16384
constexpr int FCHW = F * CHW;        // 32768
constexpr int SBLK = 256;
constexpr int NBLK_S = CHW / SBLK;   // 64

__device__ __forceinline__ float log_sigmoid(float x) {
    // jax.nn.log_sigmoid: -log1p(exp(-x)), stabilized
    return fminf(x, 0.0f) - log1pf(expf(-fabsf(x)));
}

// Kernel A: fused segment-sum (bins) + means/lnm + per-block norm partials.
// grid (NBLK_S, NC), block SBLK. B == wavefront size (64): each wave builds
// the label-match mask with one coalesced load + __ballot, then iterates
// only the set bits (avg ~B/NC iterations) with wave-uniform row addresses.
__global__ void k_fused_means(const float* __restrict__ xLE, const int* __restrict__ labels,
                              const float* __restrict__ w1, const float* __restrict__ miu,
                              const float* __restrict__ tao, const float* __restrict__ sigmas,
                              const float* __restrict__ Xw, const float* __restrict__ XLEs,
                              float* __restrict__ mt   /* [NC][CHW] */,
                              float* __restrict__ lnm  /* [NC][CHW] */,
                              float* __restrict__ pnorm/* [NC][NBLK_S][ND] */) {
    int tid  = threadIdx.x;
    int lane = tid & 63;
    int s    = blockIdx.x * SBLK + tid;   // [0, CHW)
    int nc   = blockIdx.y;

    // match mask: bit b set iff labels[b] == nc (uniform across the wave)
    int myLab = labels[lane];                       // B == 64 == wave size
    unsigned long long m = __ballot(myLab == nc);
    int cint = __popcll(m);
    float cnt     = Xw[nc] + (float)cint;
    float inv_cnt = 1.0f / cnt;

    // segment-sum restricted to matching rows; loads unconditional & pipelined
    float bin0 = XLEs[nc * FCHW + s];
    float bin1 = XLEs[nc * FCHW + CHW + s];
    unsigned long long mm = m;
    while (mm) {
        int b = __builtin_ctzll(mm);                // wave-uniform -> scalar
        mm &= mm - 1;
        bin0 += xLE[b * FCHW + s];                  // coalesced
        bin1 += xLE[b * FCHW + CHW + s];
    }

    float w1sq[ND];
    float s1 = 0.0f;
#pragma unroll
    for (int nd = 0; nd < ND; ++nd) { float t = w1[nd]; w1sq[nd] = t * t; s1 += t * t; }
    float inv_s1 = 1.0f / s1;
    float sg   = sigmas[nc];
    float sig2 = sg * sg;

    float xb0 = bin0 * inv_cnt;
    float xb1 = bin1 * inv_cnt;
    float ls0  = log_sigmoid(xb0);
    float ls1  = log_sigmoid(xb1);
    float ls1e = log_sigmoid(xb1 + EPS);

    float psum[ND];
    float theta = 0.0f, magm = 0.0f;
#pragma unroll
    for (int nd = 0; nd < ND; ++nd) {
        float m0 = miu[nd * FCHW + s];
        float m1 = miu[nd * FCHW + CHW + s];
        float d0 = ls0 - log_sigmoid(m0);
        float d1 = ls1 - log_sigmoid(m1);
        psum[nd] = d0 * d0 + d1 * d1;

        float tv   = tao[nd];
        float tao2 = tv * tv;
        float denom = 1.0f / (sig2 + tao2);
        float rt = tao2 * denom;
        float rs = sig2 * denom;
        float wn = w1sq[nd] * inv_s1;      // w1n == w2n in the reference
        theta += (xb1 * rt + m0 * rs) * wn;
        magm  += expf((rt * ls1e + rs * log_sigmoid(m1 + EPS)) * wn);
    }
    mt[nc * CHW + s]  = theta;
    lnm[nc * CHW + s] = logf(magm + EPS);

    // block-level reduction of psum -> per-block partial (no atomics, no zero-init)
#pragma unroll
    for (int nd = 0; nd < ND; ++nd) {
        float v = psum[nd];
        for (int off = 32; off > 0; off >>= 1)
            v += __shfl_down(v, off, 64);
        psum[nd] = v;
    }
    __shared__ float red[4][ND];
    int wv = tid >> 6;
    if (lane == 0) {
#pragma unroll
        for (int nd = 0; nd < ND; ++nd) red[wv][nd] = psum[nd];
    }
    __syncthreads();
    if (tid < ND) {
        int nd = tid;
        pnorm[(nc * NBLK_S + blockIdx.x) * ND + nd] =
            red[0][nd] + red[1][nd] + red[2][nd] + red[3][nd];
    }
}

// Kernel B: x_out (float4 over s) + (block 0 only) loss from norm partials.
__global__ void k_xout_loss(const float* __restrict__ xLE, const float* __restrict__ mt,
                            const float* __restrict__ lnm, const float* __restrict__ weight,
                            const int* __restrict__ labels, const float* __restrict__ Xw,
                            const float* __restrict__ tao, const float* __restrict__ sigmas,
                            const float* __restrict__ pnorm,
                            float* __restrict__ out /* [B*CHW] xout, then [ND] loss */) {
    int idx = blockIdx.x * blockDim.x + threadIdx.x;  // [0, B*CHW/4)
    int b  = idx >> 12;                                // CHW/4 = 4096 vec4 per b
    int s4 = (idx & 4095) << 2;                        // s offset, multiple of 4

    const float4 x0 = *reinterpret_cast<const float4*>(&xLE[b * FCHW + s4]);
    const float4 x1 = *reinterpret_cast<const float4*>(&xLE[b * FCHW + CHW + s4]);
    float4 lnx;
    lnx.x = logf(x1.x); lnx.y = logf(x1.y); lnx.z = logf(x1.z); lnx.w = logf(x1.w);

    float wv0 = weight[0], wv1 = weight[1];
    float w0 = wv0 * wv0, w1s = wv1 * wv1;
    float4 best = make_float4(INFINITY, INFINITY, INFINITY, INFINITY);
#pragma unroll
    for (int nc = 0; nc < NC; ++nc) {
        const float4 mt4 = *reinterpret_cast<const float4*>(&mt[nc * CHW + s4]);
        const float4 lm4 = *reinterpret_cast<const float4*>(&lnm[nc * CHW + s4]);
        best.x = fminf(best.x, w0 * fabsf(x0.x - mt4.x) + w1s * fabsf(lnx.x - lm4.x));
        best.y = fminf(best.y, w0 * fabsf(x0.y - mt4.y) + w1s * fabsf(lnx.y - lm4.y));
        best.z = fminf(best.z, w0 * fabsf(x0.z - mt4.z) + w1s * fabsf(lnx.z - lm4.z));
        best.w = fminf(best.w, w0 * fabsf(x0.w - mt4.w) + w1s * fabsf(lnx.w - lm4.w));
    }
    *reinterpret_cast<float4*>(&out[b * CHW + s4]) = best;

    if (blockIdx.x == 0 && threadIdx.x < ND) {
        int nd = threadIdx.x;
        float tv   = tao[nd];
        float tao2 = tv * tv;
        float tao4 = tao2 * tao2;
        float acc = 0.0f;
        for (int nc = 0; nc < NC; ++nc) {
            int cint = 0;
            for (int bb = 0; bb < B; ++bb) cint += (labels[bb] == nc);
            float cnt  = Xw[nc] + (float)cint;
            float sg   = sigmas[nc];
            float sig2 = sg * sg;
            float normv = 0.0f;
            for (int blk = 0; blk < NBLK_S; ++blk)
                normv += pnorm[(nc * NBLK_S + blk) * ND + nd];
            float t1 = sig2 / ((tao2 + sig2) * (tao2 + sig2));
            float t2 = sig2 * normv;
            float t3 = 2.0f * (float)CHW * (tao4 - sig2 * sig2) / cnt;
            acc += t1 * (t2 + t3);
        }
        out[B * CHW + nd] = acc / (float)NC;
    }
}

extern "C" void kernel_launch(void* const* d_in, const int* in_sizes, int n_in,
                              void* d_out, int out_size, void* d_ws, size_t ws_size,
                              hipStream_t stream) {
    const float* xLE    = (const float*)d_in[0];
    const int*   labels = (const int*)  d_in[1];
    const float* w1     = (const float*)d_in[2];
    // d_in[3] (w2) is unused: the reference computes w2n from w1.
    const float* miu    = (const float*)d_in[4];
    const float* tao    = (const float*)d_in[5];
    const float* weight = (const float*)d_in[6];
    const float* sigmas = (const float*)d_in[7];
    const float* XLEs   = (const float*)d_in[8];
    const float* Xw     = (const float*)d_in[9];

    float* out = (float*)d_out;                 // x_out [B*CHW] then loss [ND]

    float* mt    = (float*)d_ws;                // NC*CHW
    float* lnm   = mt + NC * CHW;               // NC*CHW
    float* pnorm = lnm + NC * CHW;              // NC*NBLK_S*ND

    k_fused_means<<<dim3(NBLK_S, NC), SBLK, 0, stream>>>(
        xLE, labels, w1, miu, tao, sigmas, Xw, XLEs, mt, lnm, pnorm);

    k_xout_loss<<<(B * CHW) / 4 / 256, 256, 0, stream>>>(
        xLE, mt, lnm, weight, labels, Xw, tao, sigmas, pnorm, out);
}